// Round 1
// baseline (160.340 us; speedup 1.0000x reference)
//
#include <hip/hip_runtime.h>

#define G_DIM 16384
#define N_BATCH 2048
#define IN_DIM 1024
#define NLAYER 6
#define THREADS 1024
#define GPT (G_DIM / THREADS)   // 16 gates per thread
#define ROWS_PER_BLOCK 2

struct Ptrs {
    const int*   idx[NLAYER];
    const float* w[NLAYER];
};

// ---- coefficient precompute: coef[g] = W16_TO_4 @ softmax(w[:,g]) ----
__global__ __launch_bounds__(256) void coef_kernel(const float* __restrict__ w,
                                                   float4* __restrict__ coef) {
    int g = blockIdx.x * blockDim.x + threadIdx.x;
    if (g >= G_DIM) return;
    float v[16];
    float m = -1e30f;
#pragma unroll
    for (int k = 0; k < 16; ++k) { v[k] = w[k * G_DIM + g]; m = fmaxf(m, v[k]); }
    float s = 0.f;
#pragma unroll
    for (int k = 0; k < 16; ++k) { v[k] = expf(v[k] - m); s += v[k]; }
    float inv = 1.f / s;
    // Rows of the constant 4x16 matrix, hardcoded:
    float c0 = (v[8]+v[9]+v[10]+v[11]+v[12]+v[13]+v[14]+v[15]) * inv;
    float c1 = (v[2]+v[3]+v[6]+v[7] - v[8]-v[9]-v[12]-v[13]) * inv;
    float c2 = (v[4]+v[5]+v[6]+v[7] - v[8]-v[9]-v[10]-v[11]) * inv;
    float c3 = (v[1]-v[2]-v[4]-2.f*v[6]-v[7]+v[8]+2.f*v[9]+v[11]+v[13]-v[14]) * inv;
    coef[g] = make_float4(c0, c1, c2, c3);
}

// ---- main fused kernel: 2 batch rows per block, activations resident in LDS ----
template<bool USE_COEF>
__global__ __launch_bounds__(THREADS, 1) void fused_kernel(
    const float* __restrict__ x,
    Ptrs P,
    const float4* __restrict__ coef,
    const float* __restrict__ lin_w,
    const float* __restrict__ lin_b,
    float* __restrict__ out)
{
    __shared__ float b0[G_DIM];
    __shared__ float b1[G_DIM];
    __shared__ float red0[THREADS / 64];
    __shared__ float red1[THREADS / 64];

    const int tid  = threadIdx.x;
    const int row0 = blockIdx.x * ROWS_PER_BLOCK;

    // load the two input rows (1024 floats each)
    for (int i = tid; i < IN_DIM; i += THREADS) {
        b0[i] = x[(size_t)row0 * IN_DIM + i];
        b1[i] = x[(size_t)(row0 + 1) * IN_DIM + i];
    }
    __syncthreads();

    float o0[GPT], o1[GPT];

    for (int l = 0; l < NLAYER; ++l) {
        const int2*   __restrict__ idxl = (const int2*)P.idx[l];
        const float4* __restrict__ cl   = coef + (size_t)l * G_DIM;
        const float*  __restrict__ wl   = P.w[l];

        // read phase: compute all outputs into registers
#pragma unroll
        for (int i = 0; i < GPT; ++i) {
            const int g = tid + i * THREADS;
            const int2 p = idxl[g];
            float4 c;
            if constexpr (USE_COEF) {
                c = cl[g];
            } else {
                float v[16];
                float m = -1e30f;
#pragma unroll
                for (int k = 0; k < 16; ++k) { v[k] = wl[k * G_DIM + g]; m = fmaxf(m, v[k]); }
                float s = 0.f;
#pragma unroll
                for (int k = 0; k < 16; ++k) { v[k] = expf(v[k] - m); s += v[k]; }
                float inv = 1.f / s;
                c.x = (v[8]+v[9]+v[10]+v[11]+v[12]+v[13]+v[14]+v[15]) * inv;
                c.y = (v[2]+v[3]+v[6]+v[7] - v[8]-v[9]-v[12]-v[13]) * inv;
                c.z = (v[4]+v[5]+v[6]+v[7] - v[8]-v[9]-v[10]-v[11]) * inv;
                c.w = (v[1]-v[2]-v[4]-2.f*v[6]-v[7]+v[8]+2.f*v[9]+v[11]+v[13]-v[14]) * inv;
            }
            const float A0 = b0[p.x], B0 = b0[p.y];
            const float A1 = b1[p.x], B1 = b1[p.y];
            // c0 + c1*A + c2*B + c3*A*B  ==  (c1 + c3*B)*A + (c0 + c2*B)
            o0[i] = fmaf(fmaf(c.w, B0, c.y), A0, fmaf(c.z, B0, c.x));
            o1[i] = fmaf(fmaf(c.w, B1, c.y), A1, fmaf(c.z, B1, c.x));
        }
        __syncthreads();   // all reads of this layer done

        // write phase: overwrite the same buffers
#pragma unroll
        for (int i = 0; i < GPT; ++i) {
            const int g = tid + i * THREADS;
            b0[g] = o0[i];
            b1[g] = o1[i];
        }
        __syncthreads();   // layer fully materialized
    }

    // final: out[row] = dot(x_row, lin_w) + lin_b
    float a0 = 0.f, a1 = 0.f;
#pragma unroll
    for (int i = 0; i < GPT; ++i) {
        const int g = tid + i * THREADS;
        const float lw = lin_w[g];
        a0 = fmaf(b0[g], lw, a0);
        a1 = fmaf(b1[g], lw, a1);
    }
#pragma unroll
    for (int off = 32; off > 0; off >>= 1) {
        a0 += __shfl_down(a0, off);
        a1 += __shfl_down(a1, off);
    }
    const int lane = tid & 63, wid = tid >> 6;
    if (lane == 0) { red0[wid] = a0; red1[wid] = a1; }
    __syncthreads();
    if (tid == 0) {
        float s0 = 0.f, s1 = 0.f;
#pragma unroll
        for (int k = 0; k < THREADS / 64; ++k) { s0 += red0[k]; s1 += red1[k]; }
        const float lb = lin_b[0];
        out[row0]     = s0 + lb;
        out[row0 + 1] = s1 + lb;
    }
}

extern "C" void kernel_launch(void* const* d_in, const int* in_sizes, int n_in,
                              void* d_out, int out_size, void* d_ws, size_t ws_size,
                              hipStream_t stream) {
    // setup_inputs dict order: x, idx0, w0, idx1, w1, ..., idx5, w5, lin_w, lin_b
    const float* x = (const float*)d_in[0];
    Ptrs P;
    for (int l = 0; l < NLAYER; ++l) {
        P.idx[l] = (const int*)d_in[1 + 2 * l];
        P.w[l]   = (const float*)d_in[2 + 2 * l];
    }
    const float* lin_w = (const float*)d_in[13];
    const float* lin_b = (const float*)d_in[14];
    float* out = (float*)d_out;

    const size_t coef_bytes = (size_t)NLAYER * G_DIM * sizeof(float4);
    if (ws_size >= coef_bytes) {
        float4* coef = (float4*)d_ws;
        for (int l = 0; l < NLAYER; ++l)
            coef_kernel<<<G_DIM / 256, 256, 0, stream>>>(P.w[l], coef + (size_t)l * G_DIM);
        fused_kernel<true><<<N_BATCH / ROWS_PER_BLOCK, THREADS, 0, stream>>>(
            x, P, coef, lin_w, lin_b, out);
    } else {
        fused_kernel<false><<<N_BATCH / ROWS_PER_BLOCK, THREADS, 0, stream>>>(
            x, P, nullptr, lin_w, lin_b, out);
    }
}

// Round 2
// 130.915 us; speedup vs baseline: 1.2248x; 1.2248x over previous
//
#include <hip/hip_runtime.h>

#define G_DIM 16384
#define N_BATCH 2048
#define IN_DIM 1024
#define NLAYER 6
#define THREADS 1024
#define GPT (G_DIM / THREADS)   // 16 gates per thread
#define ROWS_PER_BLOCK 2

struct Ptrs {
    const int*   idx[NLAYER];
    const float* w[NLAYER];
};

// ---- coefficient precompute (ALL layers in one launch):
//      coef[l][g] = W16_TO_4 @ softmax(w_l[:,g]) ----
__global__ __launch_bounds__(256) void coef_all_kernel(Ptrs P, float4* __restrict__ coef) {
    const int g = blockIdx.x * blockDim.x + threadIdx.x;
    const int l = blockIdx.y;
    const float* __restrict__ w = P.w[l];
    float v[16];
    float m = -1e30f;
#pragma unroll
    for (int k = 0; k < 16; ++k) { v[k] = w[k * G_DIM + g]; m = fmaxf(m, v[k]); }
    float s = 0.f;
#pragma unroll
    for (int k = 0; k < 16; ++k) { v[k] = expf(v[k] - m); s += v[k]; }
    const float inv = 1.f / s;
    float c0 = (v[8]+v[9]+v[10]+v[11]+v[12]+v[13]+v[14]+v[15]) * inv;
    float c1 = (v[2]+v[3]+v[6]+v[7] - v[8]-v[9]-v[12]-v[13]) * inv;
    float c2 = (v[4]+v[5]+v[6]+v[7] - v[8]-v[9]-v[10]-v[11]) * inv;
    float c3 = (v[1]-v[2]-v[4]-2.f*v[6]-v[7]+v[8]+2.f*v[9]+v[11]+v[13]-v[14]) * inv;
    coef[(size_t)l * G_DIM + g] = make_float4(c0, c1, c2, c3);
}

// ---- main fused kernel: 2 batch rows per block, interleaved float2 in LDS.
//      One ds_read_b64 at gather index p serves BOTH rows. ----
template<bool USE_COEF>
__global__ __launch_bounds__(THREADS, 1) void fused_kernel(
    const float* __restrict__ x,
    Ptrs P,
    const float4* __restrict__ coef,
    const float* __restrict__ lin_w,
    const float* __restrict__ lin_b,
    float* __restrict__ out)
{
    __shared__ float2 buf[G_DIM];            // 128 KB: .x = row0, .y = row1
    __shared__ float red0[THREADS / 64];
    __shared__ float red1[THREADS / 64];

    const int tid  = threadIdx.x;
    const int row0 = blockIdx.x * ROWS_PER_BLOCK;

    // load the two input rows (coalesced per-row), interleave
    for (int i = tid; i < IN_DIM; i += THREADS) {
        buf[i] = make_float2(x[(size_t)row0 * IN_DIM + i],
                             x[(size_t)(row0 + 1) * IN_DIM + i]);
    }
    __syncthreads();

    float2 o[GPT];

    for (int l = 0; l < NLAYER; ++l) {
        const int2*   __restrict__ idxl = (const int2*)P.idx[l];
        const float4* __restrict__ cl   = coef + (size_t)l * G_DIM;
        const float*  __restrict__ wl   = P.w[l];

        // read phase: compute all outputs into registers
#pragma unroll
        for (int i = 0; i < GPT; ++i) {
            const int g = tid + i * THREADS;
            const int2 p = idxl[g];
            float4 c;
            if constexpr (USE_COEF) {
                c = cl[g];
            } else {
                float v[16];
                float m = -1e30f;
#pragma unroll
                for (int k = 0; k < 16; ++k) { v[k] = wl[k * G_DIM + g]; m = fmaxf(m, v[k]); }
                float s = 0.f;
#pragma unroll
                for (int k = 0; k < 16; ++k) { v[k] = expf(v[k] - m); s += v[k]; }
                const float inv = 1.f / s;
                c.x = (v[8]+v[9]+v[10]+v[11]+v[12]+v[13]+v[14]+v[15]) * inv;
                c.y = (v[2]+v[3]+v[6]+v[7] - v[8]-v[9]-v[12]-v[13]) * inv;
                c.z = (v[4]+v[5]+v[6]+v[7] - v[8]-v[9]-v[10]-v[11]) * inv;
                c.w = (v[1]-v[2]-v[4]-2.f*v[6]-v[7]+v[8]+2.f*v[9]+v[11]+v[13]-v[14]) * inv;
            }
            const float2 Ap = buf[p.x];      // {A_row0, A_row1} one b64 read
            const float2 Bp = buf[p.y];      // {B_row0, B_row1} one b64 read
            // c0 + c1*A + c2*B + c3*A*B == (c1 + c3*B)*A + (c0 + c2*B)
            o[i].x = fmaf(fmaf(c.w, Bp.x, c.y), Ap.x, fmaf(c.z, Bp.x, c.x));
            o[i].y = fmaf(fmaf(c.w, Bp.y, c.y), Ap.y, fmaf(c.z, Bp.y, c.x));
        }
        __syncthreads();   // all reads of this layer done

        // write phase: overwrite the same buffer (b64, conflict-free stride)
#pragma unroll
        for (int i = 0; i < GPT; ++i) {
            const int g = tid + i * THREADS;
            buf[g] = o[i];
        }
        __syncthreads();   // layer fully materialized
    }

    // final: out[row] = dot(x_row, lin_w) + lin_b
    float a0 = 0.f, a1 = 0.f;
#pragma unroll
    for (int i = 0; i < GPT; ++i) {
        const int g = tid + i * THREADS;
        const float lw = lin_w[g];
        const float2 bv = buf[g];
        a0 = fmaf(bv.x, lw, a0);
        a1 = fmaf(bv.y, lw, a1);
    }
#pragma unroll
    for (int off = 32; off > 0; off >>= 1) {
        a0 += __shfl_down(a0, off);
        a1 += __shfl_down(a1, off);
    }
    const int lane = tid & 63, wid = tid >> 6;
    if (lane == 0) { red0[wid] = a0; red1[wid] = a1; }
    __syncthreads();
    if (tid == 0) {
        float s0 = 0.f, s1 = 0.f;
#pragma unroll
        for (int k = 0; k < THREADS / 64; ++k) { s0 += red0[k]; s1 += red1[k]; }
        const float lb = lin_b[0];
        out[row0]     = s0 + lb;
        out[row0 + 1] = s1 + lb;
    }
}

extern "C" void kernel_launch(void* const* d_in, const int* in_sizes, int n_in,
                              void* d_out, int out_size, void* d_ws, size_t ws_size,
                              hipStream_t stream) {
    // setup_inputs dict order: x, idx0..idx5, w0..w5, lin_w, lin_b
    // (dict insertion order: x, then per-layer idx{l}, then per-layer w{l}? —
    //  NO: loop inserts idx{l} then w{l} per l? Actually: idx{l} inserted in
    //  first loop pass then w{l}; reference signature confirms order below.)
    const float* x = (const float*)d_in[0];
    Ptrs P;
    // setup_inputs inserts, for each l: idx{l} (key f"idx{l}") and w{l} in the
    // SAME loop iteration: idx first, then w. So layout is
    // [x, idx0, w0, idx1, w1, ..., idx5, w5, lin_w, lin_b].
    for (int l = 0; l < NLAYER; ++l) {
        P.idx[l] = (const int*)d_in[1 + 2 * l];
        P.w[l]   = (const float*)d_in[2 + 2 * l];
    }
    const float* lin_w = (const float*)d_in[13];
    const float* lin_b = (const float*)d_in[14];
    float* out = (float*)d_out;

    const size_t coef_bytes = (size_t)NLAYER * G_DIM * sizeof(float4);
    if (ws_size >= coef_bytes) {
        float4* coef = (float4*)d_ws;
        dim3 cgrid(G_DIM / 256, NLAYER);
        coef_all_kernel<<<cgrid, 256, 0, stream>>>(P, coef);
        fused_kernel<true><<<N_BATCH / ROWS_PER_BLOCK, THREADS, 0, stream>>>(
            x, P, coef, lin_w, lin_b, out);
    } else {
        fused_kernel<false><<<N_BATCH / ROWS_PER_BLOCK, THREADS, 0, stream>>>(
            x, P, nullptr, lin_w, lin_b, out);
    }
}

// Round 3
// 103.640 us; speedup vs baseline: 1.5471x; 1.2632x over previous
//
#include <hip/hip_runtime.h>

#define G_DIM 16384
#define N_BATCH 2048
#define IN_DIM 1024
#define NLAYER 6
#define THREADS 1024
#define GPT 16                 // gates per thread
#define CHUNK 4
#define NCHUNK (GPT / CHUNK)
#define ROWS_PER_BLOCK 2

struct Ptrs {
    const int*   idx[NLAYER];
    const float* w[NLAYER];
};

__device__ __forceinline__ float4 softmax_coef(const float* __restrict__ w, int g) {
    float v[16];
    float m = -1e30f;
#pragma unroll
    for (int k = 0; k < 16; ++k) { v[k] = w[k * G_DIM + g]; m = fmaxf(m, v[k]); }
    float s = 0.f;
#pragma unroll
    for (int k = 0; k < 16; ++k) { v[k] = expf(v[k] - m); s += v[k]; }
    const float inv = 1.f / s;
    float4 c;
    c.x = (v[8]+v[9]+v[10]+v[11]+v[12]+v[13]+v[14]+v[15]) * inv;
    c.y = (v[2]+v[3]+v[6]+v[7] - v[8]-v[9]-v[12]-v[13]) * inv;
    c.z = (v[4]+v[5]+v[6]+v[7] - v[8]-v[9]-v[10]-v[11]) * inv;
    c.w = (v[1]-v[2]-v[4]-2.f*v[6]-v[7]+v[8]+2.f*v[9]+v[11]+v[13]-v[14]) * inv;
    return c;
}

// ---- precompute: coef[l][g] (float4) and packed idx (lo16 = A, hi16 = B) ----
__global__ __launch_bounds__(256) void pack_kernel(Ptrs P, float4* __restrict__ coef,
                                                   unsigned* __restrict__ sidx) {
    const int g = blockIdx.x * blockDim.x + threadIdx.x;
    const int l = blockIdx.y;
    coef[(size_t)l * G_DIM + g] = softmax_coef(P.w[l], g);
    const int2 p = ((const int2*)P.idx[l])[g];
    sidx[(size_t)l * G_DIM + g] = (unsigned)p.x | ((unsigned)p.y << 16);
}

// ---- main fused kernel: 2 rows/block interleaved float2 in LDS,
//      idx hoisted per layer + next-layer idx prefetch, coef chunk double-buffered ----
__global__ __launch_bounds__(THREADS, 1) void fused_ws_kernel(
    const float* __restrict__ x,
    const float4* __restrict__ coef,
    const unsigned* __restrict__ sidx,
    const float* __restrict__ lin_w,
    const float* __restrict__ lin_b,
    float* __restrict__ out)
{
    __shared__ float2 buf[G_DIM];            // 128 KB: .x = row0, .y = row1
    __shared__ float red0[THREADS / 64];
    __shared__ float red1[THREADS / 64];

    const int tid  = threadIdx.x;
    const int row0 = blockIdx.x * ROWS_PER_BLOCK;

    for (int i = tid; i < IN_DIM; i += THREADS) {
        buf[i] = make_float2(x[(size_t)row0 * IN_DIM + i],
                             x[(size_t)(row0 + 1) * IN_DIM + i]);
    }

    // hoist layer-0 packed indices while rows load
    unsigned pa[GPT];
#pragma unroll
    for (int i = 0; i < GPT; ++i) pa[i] = sidx[tid + i * THREADS];

    __syncthreads();

#pragma unroll
    for (int l = 0; l < NLAYER; ++l) {
        const float4* __restrict__ cl = coef + (size_t)l * G_DIM;
        float2 o[GPT];
        float4 c0[CHUNK], c1[CHUNK];

        // prologue: coef chunk 0
#pragma unroll
        for (int j = 0; j < CHUNK; ++j) c0[j] = cl[tid + j * THREADS];

#pragma unroll
        for (int ch = 0; ch < NCHUNK; ++ch) {
            // prefetch next coef chunk into the other buffer (static parity)
            if (ch + 1 < NCHUNK) {
#pragma unroll
                for (int j = 0; j < CHUNK; ++j) {
                    const float4 t = cl[tid + ((ch + 1) * CHUNK + j) * THREADS];
                    if (ch & 1) c0[j] = t; else c1[j] = t;
                }
            }
            // gather + fma for current chunk
#pragma unroll
            for (int j = 0; j < CHUNK; ++j) {
                const int i = ch * CHUNK + j;
                const unsigned pk = pa[i];
                const float2 Ap = buf[pk & 0xFFFFu];
                const float2 Bp = buf[pk >> 16];
                const float4 c = (ch & 1) ? c1[j] : c0[j];
                o[i].x = fmaf(fmaf(c.w, Bp.x, c.y), Ap.x, fmaf(c.z, Bp.x, c.x));
                o[i].y = fmaf(fmaf(c.w, Bp.y, c.y), Ap.y, fmaf(c.z, Bp.y, c.x));
            }
        }

        // prefetch next layer's packed indices (hides under write phase + barrier)
        unsigned pn[GPT];
        if (l + 1 < NLAYER) {
            const unsigned* __restrict__ sl = sidx + (size_t)(l + 1) * G_DIM;
#pragma unroll
            for (int i = 0; i < GPT; ++i) pn[i] = sl[tid + i * THREADS];
        }

        __syncthreads();   // all reads of this layer done

#pragma unroll
        for (int i = 0; i < GPT; ++i) buf[tid + i * THREADS] = o[i];

        __syncthreads();   // layer fully materialized

        if (l + 1 < NLAYER) {
#pragma unroll
            for (int i = 0; i < GPT; ++i) pa[i] = pn[i];
        }
    }

    // final: out[row] = dot(x_row, lin_w) + lin_b
    float a0 = 0.f, a1 = 0.f;
#pragma unroll
    for (int i = 0; i < GPT; ++i) {
        const int g = tid + i * THREADS;
        const float lw = lin_w[g];
        const float2 bv = buf[g];
        a0 = fmaf(bv.x, lw, a0);
        a1 = fmaf(bv.y, lw, a1);
    }
#pragma unroll
    for (int off = 32; off > 0; off >>= 1) {
        a0 += __shfl_down(a0, off);
        a1 += __shfl_down(a1, off);
    }
    const int lane = tid & 63, wid = tid >> 6;
    if (lane == 0) { red0[wid] = a0; red1[wid] = a1; }
    __syncthreads();
    if (tid == 0) {
        float s0 = 0.f, s1 = 0.f;
#pragma unroll
        for (int k = 0; k < THREADS / 64; ++k) { s0 += red0[k]; s1 += red1[k]; }
        const float lb = lin_b[0];
        out[row0]     = s0 + lb;
        out[row0 + 1] = s1 + lb;
    }
}

// ---- fallback (small ws): inline softmax, direct int2 idx (correctness only) ----
__global__ __launch_bounds__(THREADS, 1) void fused_fallback_kernel(
    const float* __restrict__ x, Ptrs P,
    const float* __restrict__ lin_w, const float* __restrict__ lin_b,
    float* __restrict__ out)
{
    __shared__ float2 buf[G_DIM];
    __shared__ float red0[THREADS / 64];
    __shared__ float red1[THREADS / 64];
    const int tid  = threadIdx.x;
    const int row0 = blockIdx.x * ROWS_PER_BLOCK;
    for (int i = tid; i < IN_DIM; i += THREADS)
        buf[i] = make_float2(x[(size_t)row0 * IN_DIM + i],
                             x[(size_t)(row0 + 1) * IN_DIM + i]);
    __syncthreads();
    float2 o[GPT];
    for (int l = 0; l < NLAYER; ++l) {
        const int2* __restrict__ idxl = (const int2*)P.idx[l];
#pragma unroll
        for (int i = 0; i < GPT; ++i) {
            const int g = tid + i * THREADS;
            const int2 p = idxl[g];
            const float4 c = softmax_coef(P.w[l], g);
            const float2 Ap = buf[p.x];
            const float2 Bp = buf[p.y];
            o[i].x = fmaf(fmaf(c.w, Bp.x, c.y), Ap.x, fmaf(c.z, Bp.x, c.x));
            o[i].y = fmaf(fmaf(c.w, Bp.y, c.y), Ap.y, fmaf(c.z, Bp.y, c.x));
        }
        __syncthreads();
#pragma unroll
        for (int i = 0; i < GPT; ++i) buf[tid + i * THREADS] = o[i];
        __syncthreads();
    }
    float a0 = 0.f, a1 = 0.f;
#pragma unroll
    for (int i = 0; i < GPT; ++i) {
        const int g = tid + i * THREADS;
        const float lw = lin_w[g];
        const float2 bv = buf[g];
        a0 = fmaf(bv.x, lw, a0);
        a1 = fmaf(bv.y, lw, a1);
    }
#pragma unroll
    for (int off = 32; off > 0; off >>= 1) {
        a0 += __shfl_down(a0, off);
        a1 += __shfl_down(a1, off);
    }
    const int lane = tid & 63, wid = tid >> 6;
    if (lane == 0) { red0[wid] = a0; red1[wid] = a1; }
    __syncthreads();
    if (tid == 0) {
        float s0 = 0.f, s1 = 0.f;
#pragma unroll
        for (int k = 0; k < THREADS / 64; ++k) { s0 += red0[k]; s1 += red1[k]; }
        const float lb = lin_b[0];
        out[row0]     = s0 + lb;
        out[row0 + 1] = s1 + lb;
    }
}

extern "C" void kernel_launch(void* const* d_in, const int* in_sizes, int n_in,
                              void* d_out, int out_size, void* d_ws, size_t ws_size,
                              hipStream_t stream) {
    // layout: [x, idx0, w0, idx1, w1, ..., idx5, w5, lin_w, lin_b]
    const float* x = (const float*)d_in[0];
    Ptrs P;
    for (int l = 0; l < NLAYER; ++l) {
        P.idx[l] = (const int*)d_in[1 + 2 * l];
        P.w[l]   = (const float*)d_in[2 + 2 * l];
    }
    const float* lin_w = (const float*)d_in[13];
    const float* lin_b = (const float*)d_in[14];
    float* out = (float*)d_out;

    const size_t coef_bytes = (size_t)NLAYER * G_DIM * sizeof(float4);
    const size_t sidx_bytes = (size_t)NLAYER * G_DIM * sizeof(unsigned);
    if (ws_size >= coef_bytes + sidx_bytes) {
        float4*   coef = (float4*)d_ws;
        unsigned* sidx = (unsigned*)((char*)d_ws + coef_bytes);
        dim3 cgrid(G_DIM / 256, NLAYER);
        pack_kernel<<<cgrid, 256, 0, stream>>>(P, coef, sidx);
        fused_ws_kernel<<<N_BATCH / ROWS_PER_BLOCK, THREADS, 0, stream>>>(
            x, coef, sidx, lin_w, lin_b, out);
    } else {
        fused_fallback_kernel<<<N_BATCH / ROWS_PER_BLOCK, THREADS, 0, stream>>>(
            x, P, lin_w, lin_b, out);
    }
}

// Round 4
// 103.115 us; speedup vs baseline: 1.5550x; 1.0051x over previous
//
#include <hip/hip_runtime.h>

#define G_DIM 16384
#define N_BATCH 2048
#define IN_DIM 1024
#define NLAYER 6
#define THREADS 1024
#define GPT 16                 // gates per thread
#define ROWS_PER_BLOCK 2

struct Ptrs {
    const int*   idx[NLAYER];
    const float* w[NLAYER];
};

__device__ __forceinline__ float4 softmax_coef(const float* __restrict__ w, int g) {
    float v[16];
    float m = -1e30f;
#pragma unroll
    for (int k = 0; k < 16; ++k) { v[k] = w[k * G_DIM + g]; m = fmaxf(m, v[k]); }
    float s = 0.f;
#pragma unroll
    for (int k = 0; k < 16; ++k) { v[k] = expf(v[k] - m); s += v[k]; }
    const float inv = 1.f / s;
    float4 c;
    c.x = (v[8]+v[9]+v[10]+v[11]+v[12]+v[13]+v[14]+v[15]) * inv;
    c.y = (v[2]+v[3]+v[6]+v[7] - v[8]-v[9]-v[12]-v[13]) * inv;
    c.z = (v[4]+v[5]+v[6]+v[7] - v[8]-v[9]-v[10]-v[11]) * inv;
    c.w = (v[1]-v[2]-v[4]-2.f*v[6]-v[7]+v[8]+2.f*v[9]+v[11]+v[13]-v[14]) * inv;
    return c;
}

// ---- precompute: coef[l][g] (float4) and packed idx (lo16 = A, hi16 = B) ----
__global__ __launch_bounds__(256) void pack_kernel(Ptrs P, float4* __restrict__ coef,
                                                   unsigned* __restrict__ sidx) {
    const int g = blockIdx.x * blockDim.x + threadIdx.x;
    const int l = blockIdx.y;
    coef[(size_t)l * G_DIM + g] = softmax_coef(P.w[l], g);
    const int2 p = ((const int2*)P.idx[l])[g];
    sidx[(size_t)l * G_DIM + g] = (unsigned)p.x | ((unsigned)p.y << 16);
}

// ---- main fused kernel: 2 rows/block interleaved float2 in LDS.
//      Full-depth coef prefetch: all 16 float4 loads in flight at layer start,
//      counted vmcnt waits let LDS gathers hide the L2 latency. ----
__global__ __launch_bounds__(THREADS, 4) void fused_ws_kernel(
    const float* __restrict__ x,
    const float4* __restrict__ coef,
    const unsigned* __restrict__ sidx,
    const float* __restrict__ lin_w,
    const float* __restrict__ lin_b,
    float* __restrict__ out)
{
    __shared__ float2 buf[G_DIM];            // 128 KB: .x = row0, .y = row1
    __shared__ float red0[THREADS / 64];
    __shared__ float red1[THREADS / 64];

    const int tid  = threadIdx.x;
    const int row0 = blockIdx.x * ROWS_PER_BLOCK;

    for (int i = tid; i < IN_DIM; i += THREADS) {
        buf[i] = make_float2(x[(size_t)row0 * IN_DIM + i],
                             x[(size_t)(row0 + 1) * IN_DIM + i]);
    }

    // hoist layer-0 packed indices while rows load
    unsigned pa[GPT];
#pragma unroll
    for (int i = 0; i < GPT; ++i) pa[i] = sidx[tid + i * THREADS];

    __syncthreads();

#pragma unroll
    for (int l = 0; l < NLAYER; ++l) {
        const float4* __restrict__ cl = coef + (size_t)l * G_DIM;

        // issue ALL coef loads for this layer (16 float4 in flight)
        float4 c[GPT];
#pragma unroll
        for (int i = 0; i < GPT; ++i) c[i] = cl[tid + i * THREADS];

        // gather + fma; compiler emits counted vmcnt before each c[i] use,
        // so the b64 gathers overlap the outstanding L2 loads
        float2 o[GPT];
#pragma unroll
        for (int i = 0; i < GPT; ++i) {
            const unsigned pk = pa[i];
            const float2 Ap = buf[pk & 0xFFFFu];
            const float2 Bp = buf[pk >> 16];
            o[i].x = fmaf(fmaf(c[i].w, Bp.x, c[i].y), Ap.x, fmaf(c[i].z, Bp.x, c[i].x));
            o[i].y = fmaf(fmaf(c[i].w, Bp.y, c[i].y), Ap.y, fmaf(c[i].z, Bp.y, c[i].x));
        }

        // prefetch next layer's packed indices (hides under write phase + barrier)
        unsigned pn[GPT];
        if (l + 1 < NLAYER) {
            const unsigned* __restrict__ sl = sidx + (size_t)(l + 1) * G_DIM;
#pragma unroll
            for (int i = 0; i < GPT; ++i) pn[i] = sl[tid + i * THREADS];
        }

        __syncthreads();   // all reads of this layer done

#pragma unroll
        for (int i = 0; i < GPT; ++i) buf[tid + i * THREADS] = o[i];

        __syncthreads();   // layer fully materialized

        if (l + 1 < NLAYER) {
#pragma unroll
            for (int i = 0; i < GPT; ++i) pa[i] = pn[i];
        }
    }

    // final: out[row] = dot(x_row, lin_w) + lin_b
    float a0 = 0.f, a1 = 0.f;
#pragma unroll
    for (int i = 0; i < GPT; ++i) {
        const int g = tid + i * THREADS;
        const float lw = lin_w[g];
        const float2 bv = buf[g];
        a0 = fmaf(bv.x, lw, a0);
        a1 = fmaf(bv.y, lw, a1);
    }
#pragma unroll
    for (int off = 32; off > 0; off >>= 1) {
        a0 += __shfl_down(a0, off);
        a1 += __shfl_down(a1, off);
    }
    const int lane = tid & 63, wid = tid >> 6;
    if (lane == 0) { red0[wid] = a0; red1[wid] = a1; }
    __syncthreads();
    if (tid == 0) {
        float s0 = 0.f, s1 = 0.f;
#pragma unroll
        for (int k = 0; k < THREADS / 64; ++k) { s0 += red0[k]; s1 += red1[k]; }
        const float lb = lin_b[0];
        out[row0]     = s0 + lb;
        out[row0 + 1] = s1 + lb;
    }
}

// ---- fallback (small ws): inline softmax, direct int2 idx (correctness only) ----
__global__ __launch_bounds__(THREADS, 1) void fused_fallback_kernel(
    const float* __restrict__ x, Ptrs P,
    const float* __restrict__ lin_w, const float* __restrict__ lin_b,
    float* __restrict__ out)
{
    __shared__ float2 buf[G_DIM];
    __shared__ float red0[THREADS / 64];
    __shared__ float red1[THREADS / 64];
    const int tid  = threadIdx.x;
    const int row0 = blockIdx.x * ROWS_PER_BLOCK;
    for (int i = tid; i < IN_DIM; i += THREADS)
        buf[i] = make_float2(x[(size_t)row0 * IN_DIM + i],
                             x[(size_t)(row0 + 1) * IN_DIM + i]);
    __syncthreads();
    float2 o[GPT];
    for (int l = 0; l < NLAYER; ++l) {
        const int2* __restrict__ idxl = (const int2*)P.idx[l];
#pragma unroll
        for (int i = 0; i < GPT; ++i) {
            const int g = tid + i * THREADS;
            const int2 p = idxl[g];
            const float4 c = softmax_coef(P.w[l], g);
            const float2 Ap = buf[p.x];
            const float2 Bp = buf[p.y];
            o[i].x = fmaf(fmaf(c.w, Bp.x, c.y), Ap.x, fmaf(c.z, Bp.x, c.x));
            o[i].y = fmaf(fmaf(c.w, Bp.y, c.y), Ap.y, fmaf(c.z, Bp.y, c.x));
        }
        __syncthreads();
#pragma unroll
        for (int i = 0; i < GPT; ++i) buf[tid + i * THREADS] = o[i];
        __syncthreads();
    }
    float a0 = 0.f, a1 = 0.f;
#pragma unroll
    for (int i = 0; i < GPT; ++i) {
        const int g = tid + i * THREADS;
        const float lw = lin_w[g];
        const float2 bv = buf[g];
        a0 = fmaf(bv.x, lw, a0);
        a1 = fmaf(bv.y, lw, a1);
    }
#pragma unroll
    for (int off = 32; off > 0; off >>= 1) {
        a0 += __shfl_down(a0, off);
        a1 += __shfl_down(a1, off);
    }
    const int lane = tid & 63, wid = tid >> 6;
    if (lane == 0) { red0[wid] = a0; red1[wid] = a1; }
    __syncthreads();
    if (tid == 0) {
        float s0 = 0.f, s1 = 0.f;
#pragma unroll
        for (int k = 0; k < THREADS / 64; ++k) { s0 += red0[k]; s1 += red1[k]; }
        const float lb = lin_b[0];
        out[row0]     = s0 + lb;
        out[row0 + 1] = s1 + lb;
    }
}

extern "C" void kernel_launch(void* const* d_in, const int* in_sizes, int n_in,
                              void* d_out, int out_size, void* d_ws, size_t ws_size,
                              hipStream_t stream) {
    // layout: [x, idx0, w0, idx1, w1, ..., idx5, w5, lin_w, lin_b]
    const float* x = (const float*)d_in[0];
    Ptrs P;
    for (int l = 0; l < NLAYER; ++l) {
        P.idx[l] = (const int*)d_in[1 + 2 * l];
        P.w[l]   = (const float*)d_in[2 + 2 * l];
    }
    const float* lin_w = (const float*)d_in[13];
    const float* lin_b = (const float*)d_in[14];
    float* out = (float*)d_out;

    const size_t coef_bytes = (size_t)NLAYER * G_DIM * sizeof(float4);
    const size_t sidx_bytes = (size_t)NLAYER * G_DIM * sizeof(unsigned);
    if (ws_size >= coef_bytes + sidx_bytes) {
        float4*   coef = (float4*)d_ws;
        unsigned* sidx = (unsigned*)((char*)d_ws + coef_bytes);
        dim3 cgrid(G_DIM / 256, NLAYER);
        pack_kernel<<<cgrid, 256, 0, stream>>>(P, coef, sidx);
        fused_ws_kernel<<<N_BATCH / ROWS_PER_BLOCK, THREADS, 0, stream>>>(
            x, coef, sidx, lin_w, lin_b, out);
    } else {
        fused_fallback_kernel<<<N_BATCH / ROWS_PER_BLOCK, THREADS, 0, stream>>>(
            x, P, lin_w, lin_b, out);
    }
}